// Round 1
// baseline (439.337 us; speedup 1.0000x reference)
//
#include <hip/hip_runtime.h>
#include <math.h>

// Problem constants (fixed by the reference setup)
#define SEQ   1024
#define DK    16
#define NHEAD 16
#define NBATCH 8
#define TQ    256          // queries per block == blockDim.x (1 thread = 1 query row)
#define TK    32           // keys per LDS tile
#define NKT   (SEQ / TK)   // 32 k-tiles

static __device__ __forceinline__ float fast_exp2(float x) {
#if __has_builtin(__builtin_amdgcn_exp2f)
    return __builtin_amdgcn_exp2f(x);
#else
    return exp2f(x);
#endif
}

// Block = (b, h, q-tile). Consecutive blockIdx.x vary h fastest so the 16
// heads sharing one bias/mask tile are co-resident -> L2/LLC absorbs the
// x16 bias re-read.
__global__ __launch_bounds__(256, 2)
void sdpa_kernel(const float* __restrict__ Q,
                 const float* __restrict__ K,
                 const float* __restrict__ V,
                 const int*   __restrict__ mask,   // bool -> int32 per harness
                 const float* __restrict__ bias,
                 float*       __restrict__ out) {
    __shared__ float Ks[TK][DK];          // 2 KB
    __shared__ float Vs[TK][DK];          // 2 KB
    __shared__ float Bs[TQ][TK + 1];      // 33.8 KB, +1 pad -> conflict-free row reads

    const int tid = threadIdx.x;
    const int blk = blockIdx.x;           // 0..511
    const int h   = blk & (NHEAD - 1);
    const int qt  = (blk >> 4) & 3;
    const int b   = blk >> 6;
    const int q0  = qt * TQ;

    const float LOG2E  = 1.4426950408889634f;
    const float qscale = 0.25f * LOG2E;   // 1/sqrt(16) * log2(e), folded into Q

    const size_t bh = (size_t)b * NHEAD + h;

    // Q row for this thread (pre-scaled)
    float Qr[DK];
    {
        const float4* q4 = (const float4*)(Q + (bh * SEQ + q0 + tid) * DK);
        #pragma unroll
        for (int i = 0; i < 4; ++i) {
            float4 v = q4[i];
            Qr[4*i+0] = v.x * qscale;
            Qr[4*i+1] = v.y * qscale;
            Qr[4*i+2] = v.z * qscale;
            Qr[4*i+3] = v.w * qscale;
        }
    }

    float acc[DK];
    #pragma unroll
    for (int j = 0; j < DK; ++j) acc[j] = 0.0f;
    float l = 0.0f;

    const float* Kbase = K + bh * SEQ * DK;
    const float* Vbase = V + bh * SEQ * DK;
    const float* Bbase = bias + ((size_t)b * SEQ + q0) * SEQ;  // [TQ][SEQ]
    const int*   Mbase = mask + ((size_t)b * SEQ + q0) * SEQ;

    for (int t = 0; t < NKT; ++t) {
        const int k0 = t * TK;

        // --- stage K/V tile: TK*DK = 512 floats = 128 float4 each ---
        if (tid < 128) {
            float4 kv = ((const float4*)(Kbase + (size_t)k0 * DK))[tid];
            float4 vv = ((const float4*)(Vbase + (size_t)k0 * DK))[tid];
            ((float4*)&Ks[0][0])[tid] = kv;
            ((float4*)&Vs[0][0])[tid] = vv;
        }

        // --- stage bias+mask tile: TQ*TK = 8192 floats = 2048 float4, 8/thread ---
        #pragma unroll
        for (int i = 0; i < 8; ++i) {
            int e4  = tid + i * 256;          // [0, 2048)
            int row = e4 >> 3;                // TK/4 = 8 float4 per tile row
            int c4  = e4 & 7;
            const float4 bv = *(const float4*)(Bbase + (size_t)row * SEQ + k0 + c4 * 4);
            const int4   mv = *(const int4*)  (Mbase + (size_t)row * SEQ + k0 + c4 * 4);
            float* dst = &Bs[row][c4 * 4];
            // masked -> -1e9 so exp2 underflows to exactly 0 (matches ref where
            // non-masked entries exist; fully-masked rows have prob 2^-1024)
            dst[0] = mv.x ? -1e9f : bv.x * LOG2E;
            dst[1] = mv.y ? -1e9f : bv.y * LOG2E;
            dst[2] = mv.z ? -1e9f : bv.z * LOG2E;
            dst[3] = mv.w ? -1e9f : bv.w * LOG2E;
        }
        __syncthreads();

        // --- inner loop: no-max online softmax (scores bounded ~<=18*log2e) ---
        #pragma unroll 4
        for (int kk = 0; kk < TK; ++kk) {
            float s = Bs[tid][kk];
            const float4 k0v = *(const float4*)&Ks[kk][0];
            const float4 k1v = *(const float4*)&Ks[kk][4];
            const float4 k2v = *(const float4*)&Ks[kk][8];
            const float4 k3v = *(const float4*)&Ks[kk][12];
            s = fmaf(Qr[0],  k0v.x, s); s = fmaf(Qr[1],  k0v.y, s);
            s = fmaf(Qr[2],  k0v.z, s); s = fmaf(Qr[3],  k0v.w, s);
            s = fmaf(Qr[4],  k1v.x, s); s = fmaf(Qr[5],  k1v.y, s);
            s = fmaf(Qr[6],  k1v.z, s); s = fmaf(Qr[7],  k1v.w, s);
            s = fmaf(Qr[8],  k2v.x, s); s = fmaf(Qr[9],  k2v.y, s);
            s = fmaf(Qr[10], k2v.z, s); s = fmaf(Qr[11], k2v.w, s);
            s = fmaf(Qr[12], k3v.x, s); s = fmaf(Qr[13], k3v.y, s);
            s = fmaf(Qr[14], k3v.z, s); s = fmaf(Qr[15], k3v.w, s);

            float p = fast_exp2(s);
            l += p;

            const float4 v0 = *(const float4*)&Vs[kk][0];
            const float4 v1 = *(const float4*)&Vs[kk][4];
            const float4 v2 = *(const float4*)&Vs[kk][8];
            const float4 v3 = *(const float4*)&Vs[kk][12];
            acc[0]  = fmaf(p, v0.x, acc[0]);  acc[1]  = fmaf(p, v0.y, acc[1]);
            acc[2]  = fmaf(p, v0.z, acc[2]);  acc[3]  = fmaf(p, v0.w, acc[3]);
            acc[4]  = fmaf(p, v1.x, acc[4]);  acc[5]  = fmaf(p, v1.y, acc[5]);
            acc[6]  = fmaf(p, v1.z, acc[6]);  acc[7]  = fmaf(p, v1.w, acc[7]);
            acc[8]  = fmaf(p, v2.x, acc[8]);  acc[9]  = fmaf(p, v2.y, acc[9]);
            acc[10] = fmaf(p, v2.z, acc[10]); acc[11] = fmaf(p, v2.w, acc[11]);
            acc[12] = fmaf(p, v3.x, acc[12]); acc[13] = fmaf(p, v3.y, acc[13]);
            acc[14] = fmaf(p, v3.z, acc[14]); acc[15] = fmaf(p, v3.w, acc[15]);
        }
        __syncthreads();
    }

    const float inv = 1.0f / l;
    float4* o4 = (float4*)(out + (bh * SEQ + q0 + tid) * DK);
    #pragma unroll
    for (int i = 0; i < 4; ++i) {
        float4 v;
        v.x = acc[4*i+0] * inv;
        v.y = acc[4*i+1] * inv;
        v.z = acc[4*i+2] * inv;
        v.w = acc[4*i+3] * inv;
        o4[i] = v;
    }
}

extern "C" void kernel_launch(void* const* d_in, const int* in_sizes, int n_in,
                              void* d_out, int out_size, void* d_ws, size_t ws_size,
                              hipStream_t stream) {
    const float* Q    = (const float*)d_in[0];
    const float* K    = (const float*)d_in[1];
    const float* V    = (const float*)d_in[2];
    const int*   mask = (const int*)  d_in[3];
    const float* bias = (const float*)d_in[4];
    float* out = (float*)d_out;

    const int nblocks = NBATCH * NHEAD * (SEQ / TQ);  // 8*16*4 = 512
    sdpa_kernel<<<nblocks, TQ, 0, stream>>>(Q, K, V, mask, bias, out);
}

// Round 2
// 313.874 us; speedup vs baseline: 1.3997x; 1.3997x over previous
//
#include <hip/hip_runtime.h>
#include <math.h>

// Problem constants (fixed by the reference setup)
#define SEQ    1024
#define DK     16
#define NHEAD  16
#define NBATCH 8
#define THREADS 256
#define QPT    4                 // queries per thread (pass1)
#define KQ     4                 // key-split factor (partials)
#define KPB    (SEQ / KQ)        // 256 keys per block
#define TK     16                // keys per LDS tile
#define NKT    (KPB / TK)        // 16 k-tiles per block
#define BS_STRIDE 17             // bias tile row stride (odd -> 2-way reads = free)
#define NROWS  (NBATCH * NHEAD * SEQ)   // 131072 output rows

static __device__ __forceinline__ float fast_exp2(float x) {
#if __has_builtin(__builtin_amdgcn_exp2f)
    return __builtin_amdgcn_exp2f(x);
#else
    return exp2f(x);
#endif
}

// ---------------- Pass 1: partial attention over one key-quarter -------------
// Grid 512 = 8 b x 16 h x 4 kq, swizzled so the 16 head-blocks sharing one
// bias quarter land on one XCD (blockIdx % 8 == XCD assumed round-robin).
// Block: 256 threads x 4 queries = all 1024 queries; keys [kq*256, kq*256+256).
// LDS/block = 68K bias + 1K K + 1K V -> 2 blocks/CU, 8 waves/CU.
__global__ __launch_bounds__(256, 2)
void sdpa_pass1(const float* __restrict__ Q,
                const float* __restrict__ K,
                const float* __restrict__ V,
                const int*   __restrict__ mask,
                const float* __restrict__ bias,
                float*       __restrict__ accW,   // [KQ][NROWS][DK]
                float*       __restrict__ lW) {   // [KQ][NROWS]
    __shared__ float Ks[TK][DK];                  // 1 KB
    __shared__ float Vs[TK][DK];                  // 1 KB
    __shared__ float Bs[SEQ][BS_STRIDE];          // 68 KB

    const int tid = threadIdx.x;
    const int blk = blockIdx.x;
    // swizzle decode: group g=(b,kq) pinned to XCD g%8; j enumerates heads.
    const int xcd = blk & 7;
    const int j   = blk >> 3;
    const int h   = j & (NHEAD - 1);
    const int ghi = j >> 4;              // 0..3
    const int g   = ghi * 8 + xcd;       // 0..31
    const int b   = g >> 2;
    const int kq  = g & 3;

    const float LOG2E  = 1.4426950408889634f;
    const float qscale = 0.25f * LOG2E;  // 1/sqrt(16) * log2(e) folded into Q

    const size_t bh = (size_t)b * NHEAD + h;

    // 4 pre-scaled Q rows: q = tid + 256*r
    float Qr[QPT][DK];
    #pragma unroll
    for (int r = 0; r < QPT; ++r) {
        const float4* q4 = (const float4*)(Q + (bh * SEQ + tid + 256 * r) * DK);
        #pragma unroll
        for (int i = 0; i < 4; ++i) {
            float4 v = q4[i];
            Qr[r][4*i+0] = v.x * qscale;
            Qr[r][4*i+1] = v.y * qscale;
            Qr[r][4*i+2] = v.z * qscale;
            Qr[r][4*i+3] = v.w * qscale;
        }
    }

    float acc[QPT][DK];
    float lacc[QPT];
    #pragma unroll
    for (int r = 0; r < QPT; ++r) {
        lacc[r] = 0.0f;
        #pragma unroll
        for (int d = 0; d < DK; ++d) acc[r][d] = 0.0f;
    }

    const float* Kbase = K + (bh * SEQ + (size_t)kq * KPB) * DK;
    const float* Vbase = V + (bh * SEQ + (size_t)kq * KPB) * DK;
    const float* Bbase = bias + (size_t)b * SEQ * SEQ;
    const int*   Mbase = mask + (size_t)b * SEQ * SEQ;

    for (int t = 0; t < NKT; ++t) {
        const int kcol0 = kq * KPB + t * TK;

        // stage K/V tile: 16 keys x 16 d = 64 float4 each
        if (tid < 64) {
            ((float4*)&Ks[0][0])[tid] = ((const float4*)Kbase)[t * 64 + tid];
        } else if (tid < 128) {
            ((float4*)&Vs[0][0])[tid - 64] = ((const float4*)Vbase)[t * 64 + (tid - 64)];
        }

        // stage bias+mask tile: 1024 rows x 16 cols. Lane-consecutive rows ->
        // LDS write banks 2-way only (free); 64B HBM lines fully consumed
        // across the c4 sweep.
        #pragma unroll
        for (int i = 0; i < 16; ++i) {
            const int row = tid + (i & 3) * 256;   // query row
            const int c4  = i >> 2;                // float4 column within tile
            const float4 bv = *(const float4*)(Bbase + (size_t)row * SEQ + kcol0 + c4 * 4);
            const int4   mv = *(const int4*)  (Mbase + (size_t)row * SEQ + kcol0 + c4 * 4);
            float* dst = &Bs[row][c4 * 4];
            dst[0] = mv.x ? -1e9f : bv.x * LOG2E;
            dst[1] = mv.y ? -1e9f : bv.y * LOG2E;
            dst[2] = mv.z ? -1e9f : bv.z * LOG2E;
            dst[3] = mv.w ? -1e9f : bv.w * LOG2E;
        }
        __syncthreads();

        #pragma unroll 4
        for (int kk = 0; kk < TK; ++kk) {
            const float4 k0 = *(const float4*)&Ks[kk][0];
            const float4 k1 = *(const float4*)&Ks[kk][4];
            const float4 k2 = *(const float4*)&Ks[kk][8];
            const float4 k3 = *(const float4*)&Ks[kk][12];
            const float4 v0 = *(const float4*)&Vs[kk][0];
            const float4 v1 = *(const float4*)&Vs[kk][4];
            const float4 v2 = *(const float4*)&Vs[kk][8];
            const float4 v3 = *(const float4*)&Vs[kk][12];
            #pragma unroll
            for (int r = 0; r < QPT; ++r) {
                float s = Bs[tid + 256 * r][kk];
                s = fmaf(Qr[r][0],  k0.x, s); s = fmaf(Qr[r][1],  k0.y, s);
                s = fmaf(Qr[r][2],  k0.z, s); s = fmaf(Qr[r][3],  k0.w, s);
                s = fmaf(Qr[r][4],  k1.x, s); s = fmaf(Qr[r][5],  k1.y, s);
                s = fmaf(Qr[r][6],  k1.z, s); s = fmaf(Qr[r][7],  k1.w, s);
                s = fmaf(Qr[r][8],  k2.x, s); s = fmaf(Qr[r][9],  k2.y, s);
                s = fmaf(Qr[r][10], k2.z, s); s = fmaf(Qr[r][11], k2.w, s);
                s = fmaf(Qr[r][12], k3.x, s); s = fmaf(Qr[r][13], k3.y, s);
                s = fmaf(Qr[r][14], k3.z, s); s = fmaf(Qr[r][15], k3.w, s);

                const float p = fast_exp2(s);
                lacc[r] += p;

                acc[r][0]  = fmaf(p, v0.x, acc[r][0]);
                acc[r][1]  = fmaf(p, v0.y, acc[r][1]);
                acc[r][2]  = fmaf(p, v0.z, acc[r][2]);
                acc[r][3]  = fmaf(p, v0.w, acc[r][3]);
                acc[r][4]  = fmaf(p, v1.x, acc[r][4]);
                acc[r][5]  = fmaf(p, v1.y, acc[r][5]);
                acc[r][6]  = fmaf(p, v1.z, acc[r][6]);
                acc[r][7]  = fmaf(p, v1.w, acc[r][7]);
                acc[r][8]  = fmaf(p, v2.x, acc[r][8]);
                acc[r][9]  = fmaf(p, v2.y, acc[r][9]);
                acc[r][10] = fmaf(p, v2.z, acc[r][10]);
                acc[r][11] = fmaf(p, v2.w, acc[r][11]);
                acc[r][12] = fmaf(p, v3.x, acc[r][12]);
                acc[r][13] = fmaf(p, v3.y, acc[r][13]);
                acc[r][14] = fmaf(p, v3.z, acc[r][14]);
                acc[r][15] = fmaf(p, v3.w, acc[r][15]);
            }
        }
        __syncthreads();
    }

    // write partials (unnormalized)
    #pragma unroll
    for (int r = 0; r < QPT; ++r) {
        const size_t row = bh * SEQ + tid + 256 * r;
        float4* o4 = (float4*)(accW + ((size_t)kq * NROWS + row) * DK);
        #pragma unroll
        for (int i = 0; i < 4; ++i) {
            float4 v;
            v.x = acc[r][4*i+0]; v.y = acc[r][4*i+1];
            v.z = acc[r][4*i+2]; v.w = acc[r][4*i+3];
            o4[i] = v;
        }
        lW[(size_t)kq * NROWS + row] = lacc[r];
    }
}

// ---------------- Pass 2: combine 4 partials and normalize -------------------
__global__ __launch_bounds__(256)
void sdpa_pass2(const float* __restrict__ accW, const float* __restrict__ lW,
                float* __restrict__ out) {
    const int i   = blockIdx.x * 256 + threadIdx.x;  // float4 index
    const int row = i >> 2;
    const int c   = (i & 3) * 4;
    const float l = lW[row] + lW[NROWS + row] + lW[2 * NROWS + row] + lW[3 * NROWS + row];
    float4 s = *(const float4*)(accW + ((size_t)row) * DK + c);
    #pragma unroll
    for (int p = 1; p < KQ; ++p) {
        const float4 a = *(const float4*)(accW + ((size_t)p * NROWS + row) * DK + c);
        s.x += a.x; s.y += a.y; s.z += a.z; s.w += a.w;
    }
    const float inv = 1.0f / l;
    float4 o; o.x = s.x * inv; o.y = s.y * inv; o.z = s.z * inv; o.w = s.w * inv;
    *(float4*)(out + (size_t)row * DK + c) = o;
}

// ---------------- Fallback: round-1 single-pass kernel (small ws) ------------
#define FTQ 256
#define FTK 32
__global__ __launch_bounds__(256, 2)
void sdpa_fallback(const float* __restrict__ Q, const float* __restrict__ K,
                   const float* __restrict__ V, const int* __restrict__ mask,
                   const float* __restrict__ bias, float* __restrict__ out) {
    __shared__ float Ks[FTK][DK];
    __shared__ float Vs[FTK][DK];
    __shared__ float Bs[FTQ][FTK + 1];

    const int tid = threadIdx.x;
    const int blk = blockIdx.x;
    const int h   = blk & (NHEAD - 1);
    const int qt  = (blk >> 4) & 3;
    const int b   = blk >> 6;
    const int q0  = qt * FTQ;
    const float LOG2E  = 1.4426950408889634f;
    const float qscale = 0.25f * LOG2E;
    const size_t bh = (size_t)b * NHEAD + h;

    float Qr[DK];
    {
        const float4* q4 = (const float4*)(Q + (bh * SEQ + q0 + tid) * DK);
        #pragma unroll
        for (int i = 0; i < 4; ++i) {
            float4 v = q4[i];
            Qr[4*i+0] = v.x * qscale; Qr[4*i+1] = v.y * qscale;
            Qr[4*i+2] = v.z * qscale; Qr[4*i+3] = v.w * qscale;
        }
    }
    float acc[DK];
    #pragma unroll
    for (int d = 0; d < DK; ++d) acc[d] = 0.0f;
    float l = 0.0f;

    const float* Kbase = K + bh * SEQ * DK;
    const float* Vbase = V + bh * SEQ * DK;
    const float* Bbase = bias + ((size_t)b * SEQ + q0) * SEQ;
    const int*   Mbase = mask + ((size_t)b * SEQ + q0) * SEQ;

    for (int t = 0; t < SEQ / FTK; ++t) {
        const int k0 = t * FTK;
        if (tid < 128) {
            float4 kv = ((const float4*)(Kbase + (size_t)k0 * DK))[tid];
            float4 vv = ((const float4*)(Vbase + (size_t)k0 * DK))[tid];
            ((float4*)&Ks[0][0])[tid] = kv;
            ((float4*)&Vs[0][0])[tid] = vv;
        }
        #pragma unroll
        for (int i = 0; i < 8; ++i) {
            int e4 = tid + i * 256, row = e4 >> 3, c4 = e4 & 7;
            const float4 bv = *(const float4*)(Bbase + (size_t)row * SEQ + k0 + c4 * 4);
            const int4   mv = *(const int4*)  (Mbase + (size_t)row * SEQ + k0 + c4 * 4);
            float* dst = &Bs[row][c4 * 4];
            dst[0] = mv.x ? -1e9f : bv.x * LOG2E;
            dst[1] = mv.y ? -1e9f : bv.y * LOG2E;
            dst[2] = mv.z ? -1e9f : bv.z * LOG2E;
            dst[3] = mv.w ? -1e9f : bv.w * LOG2E;
        }
        __syncthreads();
        #pragma unroll 4
        for (int kk = 0; kk < FTK; ++kk) {
            float s = Bs[tid][kk];
            const float4 k0v = *(const float4*)&Ks[kk][0];
            const float4 k1v = *(const float4*)&Ks[kk][4];
            const float4 k2v = *(const float4*)&Ks[kk][8];
            const float4 k3v = *(const float4*)&Ks[kk][12];
            s = fmaf(Qr[0],  k0v.x, s); s = fmaf(Qr[1],  k0v.y, s);
            s = fmaf(Qr[2],  k0v.z, s); s = fmaf(Qr[3],  k0v.w, s);
            s = fmaf(Qr[4],  k1v.x, s); s = fmaf(Qr[5],  k1v.y, s);
            s = fmaf(Qr[6],  k1v.z, s); s = fmaf(Qr[7],  k1v.w, s);
            s = fmaf(Qr[8],  k2v.x, s); s = fmaf(Qr[9],  k2v.y, s);
            s = fmaf(Qr[10], k2v.z, s); s = fmaf(Qr[11], k2v.w, s);
            s = fmaf(Qr[12], k3v.x, s); s = fmaf(Qr[13], k3v.y, s);
            s = fmaf(Qr[14], k3v.z, s); s = fmaf(Qr[15], k3v.w, s);
            float p = fast_exp2(s);
            l += p;
            const float4 v0 = *(const float4*)&Vs[kk][0];
            const float4 v1 = *(const float4*)&Vs[kk][4];
            const float4 v2 = *(const float4*)&Vs[kk][8];
            const float4 v3 = *(const float4*)&Vs[kk][12];
            acc[0]  = fmaf(p, v0.x, acc[0]);  acc[1]  = fmaf(p, v0.y, acc[1]);
            acc[2]  = fmaf(p, v0.z, acc[2]);  acc[3]  = fmaf(p, v0.w, acc[3]);
            acc[4]  = fmaf(p, v1.x, acc[4]);  acc[5]  = fmaf(p, v1.y, acc[5]);
            acc[6]  = fmaf(p, v1.z, acc[6]);  acc[7]  = fmaf(p, v1.w, acc[7]);
            acc[8]  = fmaf(p, v2.x, acc[8]);  acc[9]  = fmaf(p, v2.y, acc[9]);
            acc[10] = fmaf(p, v2.z, acc[10]); acc[11] = fmaf(p, v2.w, acc[11]);
            acc[12] = fmaf(p, v3.x, acc[12]); acc[13] = fmaf(p, v3.y, acc[13]);
            acc[14] = fmaf(p, v3.z, acc[14]); acc[15] = fmaf(p, v3.w, acc[15]);
        }
        __syncthreads();
    }
    const float inv = 1.0f / l;
    float4* o4 = (float4*)(out + (bh * SEQ + q0 + tid) * DK);
    #pragma unroll
    for (int i = 0; i < 4; ++i) {
        float4 v;
        v.x = acc[4*i+0] * inv; v.y = acc[4*i+1] * inv;
        v.z = acc[4*i+2] * inv; v.w = acc[4*i+3] * inv;
        o4[i] = v;
    }
}

extern "C" void kernel_launch(void* const* d_in, const int* in_sizes, int n_in,
                              void* d_out, int out_size, void* d_ws, size_t ws_size,
                              hipStream_t stream) {
    const float* Q    = (const float*)d_in[0];
    const float* K    = (const float*)d_in[1];
    const float* V    = (const float*)d_in[2];
    const int*   mask = (const int*)  d_in[3];
    const float* bias = (const float*)d_in[4];
    float* out = (float*)d_out;

    const size_t accBytes = (size_t)KQ * NROWS * DK * sizeof(float);  // 33.55 MB
    const size_t lBytes   = (size_t)KQ * NROWS * sizeof(float);       //  2.10 MB

    if (ws_size >= accBytes + lBytes) {
        float* accW = (float*)d_ws;
        float* lW   = (float*)((char*)d_ws + accBytes);
        sdpa_pass1<<<NBATCH * NHEAD * KQ, THREADS, 0, stream>>>(Q, K, V, mask, bias, accW, lW);
        sdpa_pass2<<<(NROWS * DK / 4) / 256, 256, 0, stream>>>(accW, lW, out);
    } else {
        sdpa_fallback<<<NBATCH * NHEAD * (SEQ / FTQ), FTQ, 0, stream>>>(Q, K, V, mask, bias, out);
    }
}

// Round 3
// 237.114 us; speedup vs baseline: 1.8529x; 1.3237x over previous
//
#include <hip/hip_runtime.h>
#include <math.h>

#define SEQ    1024
#define DK     16
#define NHEAD  16
#define NBATCH 8
#define KQ     4                        // key-split factor
#define KPB    (SEQ / KQ)               // 256 keys per pass1 block
#define NROWS  (NBATCH * NHEAD * SEQ)   // 131072 output rows
#define LOG2E  1.4426950408889634f

typedef __attribute__((ext_vector_type(4))) short  short4v;
typedef __attribute__((ext_vector_type(4))) float  float4v;
typedef __attribute__((ext_vector_type(2))) unsigned int uint2v;

static __device__ __forceinline__ float fast_exp2(float x) {
#if __has_builtin(__builtin_amdgcn_exp2f)
    return __builtin_amdgcn_exp2f(x);
#else
    return exp2f(x);
#endif
}

// D = A*B + C, 16x16x16 bf16 (K=16 == d_k). A/B: 4 bf16/lane, C/D: 4 f32/lane.
static __device__ __forceinline__ float4v mfma16(short4v a, short4v b, float4v c) {
#if __has_builtin(__builtin_amdgcn_mfma_f32_16x16x16bf16_1k)
    return __builtin_amdgcn_mfma_f32_16x16x16bf16_1k(a, b, c, 0, 0, 0);
#else
    float4v d = c;
    asm volatile("v_mfma_f32_16x16x16_bf16 %0, %1, %2, %0" : "+v"(d) : "v"(a), "v"(b));
    return d;
#endif
}

static __device__ __forceinline__ unsigned bf16_rne(float x) {
    unsigned u = __float_as_uint(x);
    return (u + 0x7FFFu + ((u >> 16) & 1u)) >> 16;
}
static __device__ __forceinline__ float bf16_to_f(unsigned b) {
    return __uint_as_float(b << 16);
}

// ---------- Prep A: Q -> scaled bf16 hi/lo, K -> bf16 hi/lo ------------------
__global__ __launch_bounds__(256)
void prep_qk(const float* __restrict__ Q, const float* __restrict__ K,
             short* __restrict__ Qhi, short* __restrict__ Qlo,
             short* __restrict__ Khi, short* __restrict__ Klo) {
    const int i4 = blockIdx.x * 256 + threadIdx.x;      // float4 index
    const float qsc = 0.25f * LOG2E;                    // fold scale*log2e into Q
    float4 q = ((const float4*)Q)[i4];
    q.x *= qsc; q.y *= qsc; q.z *= qsc; q.w *= qsc;
    float4 k = ((const float4*)K)[i4];
    short4v qh, ql, kh, kl;
    {
        float v[4] = {q.x, q.y, q.z, q.w};
        #pragma unroll
        for (int e = 0; e < 4; ++e) {
            unsigned h = bf16_rne(v[e]);
            qh[e] = (short)h;
            ql[e] = (short)bf16_rne(v[e] - bf16_to_f(h));
        }
        float w[4] = {k.x, k.y, k.z, k.w};
        #pragma unroll
        for (int e = 0; e < 4; ++e) {
            unsigned h = bf16_rne(w[e]);
            kh[e] = (short)h;
            kl[e] = (short)bf16_rne(w[e] - bf16_to_f(h));
        }
    }
    ((short4v*)Qhi)[i4] = qh;
    ((short4v*)Qlo)[i4] = ql;
    ((short4v*)Khi)[i4] = kh;
    ((short4v*)Klo)[i4] = kl;
}

// ---------- Prep B: V -> Vt bf16, [B*H, d, s] (transposed) -------------------
__global__ __launch_bounds__(256)
void prep_vt(const float* __restrict__ V, short* __restrict__ Vt) {
    __shared__ float Vs[64][17];
    const int t  = threadIdx.x;
    const int bh = blockIdx.x >> 4;
    const int s0 = (blockIdx.x & 15) * 64;
    // coalesced read: 64 s-rows x 16 d = 256 float4
    {
        const int row = t >> 2, c4 = t & 3;
        float4 v = ((const float4*)V)[((size_t)bh * SEQ + s0 + row) * 4 + c4];
        Vs[row][c4 * 4 + 0] = v.x; Vs[row][c4 * 4 + 1] = v.y;
        Vs[row][c4 * 4 + 2] = v.z; Vs[row][c4 * 4 + 3] = v.w;
    }
    __syncthreads();
    // coalesced write: lane-consecutive s
    const int d = t >> 4, sg = t & 15;
    short4v o;
    #pragma unroll
    for (int i = 0; i < 4; ++i) o[i] = (short)bf16_rne(Vs[sg * 4 + i][d]);
    ((short4v*)Vt)[(((size_t)bh * DK + d) * SEQ + s0) / 4 + sg] = o;
}

// ---------- Pass 1: MFMA flash attention over one key-quarter ----------------
// Block = (b, qt 64-query tile, kq quarter). 512 blocks x 256 thr (4 waves).
// Wave w owns q rows [q0+16w, +16). Per (16-key tile, head): 4 MFMAs.
// S^T = K*Q^T via mfma -> C-layout == A-layout of P for PV mfma (no LDS P).
__global__ __launch_bounds__(256, 2)
void sdpa_mfma_pass1(const short* __restrict__ Qhi, const short* __restrict__ Qlo,
                     const short* __restrict__ Khi, const short* __restrict__ Klo,
                     const short* __restrict__ Vt,
                     const int*   __restrict__ mask, const float* __restrict__ bias,
                     float* __restrict__ accW, float* __restrict__ lW) {
    __shared__ float Bs[64][65];                        // bias+mask tile, 16.6 KB

    const int tid  = threadIdx.x;
    const int wave = tid >> 6;
    const int lane = tid & 63;
    const int n    = lane & 15;                         // col (q for S^T, d for PV)
    const int g    = lane >> 4;                         // 4-row group

    const int b  = blockIdx.x >> 6;
    const int kq = (blockIdx.x >> 4) & 3;
    const int qt = blockIdx.x & 15;
    const int q0 = qt * 64;
    const int k0 = kq * KPB;

    // Q B-frags for all 16 heads: lane holds Q[q=q0+16w+n][d=4g..4g+3]
    short4v qh[NHEAD], ql[NHEAD];
    {
        const int qrow = q0 + wave * 16 + n;
        #pragma unroll
        for (int h = 0; h < NHEAD; ++h) {
            const size_t base = (((size_t)b * NHEAD + h) * SEQ + qrow) * DK + g * 4;
            qh[h] = *(const short4v*)(Qhi + base);
            ql[h] = *(const short4v*)(Qlo + base);
        }
    }

    float4v acc[NHEAD];
    float   lsum[NHEAD];
    #pragma unroll
    for (int h = 0; h < NHEAD; ++h) {
        acc[h] = (float4v){0.f, 0.f, 0.f, 0.f};
        lsum[h] = 0.f;
    }

    for (int kc = 0; kc < 4; ++kc) {
        const int kb = k0 + kc * 64;
        __syncthreads();                                // prior reads done
        // stage bias+mask [64 q][64 k]; transform once, reused by 16 heads
        #pragma unroll
        for (int i = 0; i < 4; ++i) {
            const int idx = tid + i * 256;              // 0..1023
            const int row = idx >> 4;                   // q-local
            const int c4  = idx & 15;                   // float4 col
            const size_t ga = ((size_t)b * SEQ + q0 + row) * SEQ + kb + c4 * 4;
            const float4 bv = *(const float4*)(bias + ga);
            const int4   mv = *(const int4*)(mask + ga);
            float* dst = &Bs[row][c4 * 4];
            dst[0] = mv.x ? -1e9f : bv.x * LOG2E;
            dst[1] = mv.y ? -1e9f : bv.y * LOG2E;
            dst[2] = mv.z ? -1e9f : bv.z * LOG2E;
            dst[3] = mv.w ? -1e9f : bv.w * LOG2E;
        }
        __syncthreads();

        for (int kt = 0; kt < 4; ++kt) {
            const int kl16 = kt * 16;
            // bias for this wave's q-col and the lane's 4 keys (rows of S^T)
            const int qloc = wave * 16 + n;
            const float b0 = Bs[qloc][kl16 + g * 4 + 0];
            const float b1 = Bs[qloc][kl16 + g * 4 + 1];
            const float b2 = Bs[qloc][kl16 + g * 4 + 2];
            const float b3 = Bs[qloc][kl16 + g * 4 + 3];
            const int krow = kb + kl16 + n;             // A-frag key row

            #pragma unroll
            for (int h = 0; h < NHEAD; ++h) {
                const size_t bh = (size_t)b * NHEAD + h;
                const size_t ka = (bh * SEQ + krow) * DK + g * 4;
                const short4v khi = *(const short4v*)(Khi + ka);
                const short4v klo = *(const short4v*)(Klo + ka);
                const size_t va = (bh * DK + n) * SEQ + kb + kl16 + g * 4;
                const short4v vtf = *(const short4v*)(Vt + va);

                // S^T = Khi*Qhi + Khi*Qlo + Klo*Qhi  (fp32-accurate scores)
                float4v s = (float4v){0.f, 0.f, 0.f, 0.f};
                s = mfma16(klo, qh[h], s);
                s = mfma16(khi, ql[h], s);
                s = mfma16(khi, qh[h], s);

                const float p0 = fast_exp2(s[0] + b0);
                const float p1 = fast_exp2(s[1] + b1);
                const float p2 = fast_exp2(s[2] + b2);
                const float p3 = fast_exp2(s[3] + b3);
                lsum[h] += (p0 + p1) + (p2 + p3);

                // pack P to bf16 A-frag (round-half-up)
                const unsigned u0 = __float_as_uint(p0) + 0x8000u;
                const unsigned u1 = __float_as_uint(p1) + 0x8000u;
                const unsigned u2 = __float_as_uint(p2) + 0x8000u;
                const unsigned u3 = __float_as_uint(p3) + 0x8000u;
                uint2v pu;
                pu.x = (u1 & 0xFFFF0000u) | (u0 >> 16);
                pu.y = (u3 & 0xFFFF0000u) | (u2 >> 16);
                const short4v pf = __builtin_bit_cast(short4v, pu);

                acc[h] = mfma16(pf, vtf, acc[h]);       // O += P * V
            }
        }
    }

    // epilogue: reduce l across the 4 lane-groups, write partials
    #pragma unroll
    for (int h = 0; h < NHEAD; ++h) {
        float l = lsum[h];
        l += __shfl_xor(l, 16, 64);
        l += __shfl_xor(l, 32, 64);
        const size_t obase = (size_t)kq * NROWS +
                             (((size_t)b * NHEAD + h) * SEQ) + q0 + wave * 16;
        #pragma unroll
        for (int r = 0; r < 4; ++r)
            accW[(obase + g * 4 + r) * DK + n] = acc[h][r];
        if (lane < 16) lW[obase + n] = l;
    }
}

// ---------- Pass 2: combine 4 partials and normalize -------------------------
__global__ __launch_bounds__(256)
void sdpa_pass2(const float* __restrict__ accW, const float* __restrict__ lW,
                float* __restrict__ out) {
    const int i   = blockIdx.x * 256 + threadIdx.x;  // float4 index
    const int row = i >> 2;
    const int c   = (i & 3) * 4;
    const float l = lW[row] + lW[NROWS + row] + lW[2 * NROWS + row] + lW[3 * NROWS + row];
    float4 s = *(const float4*)(accW + ((size_t)row) * DK + c);
    #pragma unroll
    for (int p = 1; p < KQ; ++p) {
        const float4 a = *(const float4*)(accW + ((size_t)p * NROWS + row) * DK + c);
        s.x += a.x; s.y += a.y; s.z += a.z; s.w += a.w;
    }
    const float inv = 1.0f / l;
    float4 o; o.x = s.x * inv; o.y = s.y * inv; o.z = s.z * inv; o.w = s.w * inv;
    *(float4*)(out + (size_t)row * DK + c) = o;
}

// ---------- Fallback: round-1 single-pass kernel (small ws) ------------------
#define FTQ 256
#define FTK 32
__global__ __launch_bounds__(256, 2)
void sdpa_fallback(const float* __restrict__ Q, const float* __restrict__ K,
                   const float* __restrict__ V, const int* __restrict__ mask,
                   const float* __restrict__ bias, float* __restrict__ out) {
    __shared__ float Ks[FTK][DK];
    __shared__ float Vs[FTK][DK];
    __shared__ float Bsf[FTQ][FTK + 1];

    const int tid = threadIdx.x;
    const int blk = blockIdx.x;
    const int h   = blk & (NHEAD - 1);
    const int qt  = (blk >> 4) & 3;
    const int b   = blk >> 6;
    const int q0  = qt * FTQ;
    const float qscale = 0.25f * LOG2E;
    const size_t bh = (size_t)b * NHEAD + h;

    float Qr[DK];
    {
        const float4* q4 = (const float4*)(Q + (bh * SEQ + q0 + tid) * DK);
        #pragma unroll
        for (int i = 0; i < 4; ++i) {
            float4 v = q4[i];
            Qr[4*i+0] = v.x * qscale; Qr[4*i+1] = v.y * qscale;
            Qr[4*i+2] = v.z * qscale; Qr[4*i+3] = v.w * qscale;
        }
    }
    float acc[DK];
    #pragma unroll
    for (int d = 0; d < DK; ++d) acc[d] = 0.0f;
    float l = 0.0f;

    const float* Kbase = K + bh * SEQ * DK;
    const float* Vbase = V + bh * SEQ * DK;
    const float* Bbase = bias + ((size_t)b * SEQ + q0) * SEQ;
    const int*   Mbase = mask + ((size_t)b * SEQ + q0) * SEQ;

    for (int t = 0; t < SEQ / FTK; ++t) {
        const int k0 = t * FTK;
        if (tid < 128) {
            float4 kv = ((const float4*)(Kbase + (size_t)k0 * DK))[tid];
            float4 vv = ((const float4*)(Vbase + (size_t)k0 * DK))[tid];
            ((float4*)&Ks[0][0])[tid] = kv;
            ((float4*)&Vs[0][0])[tid] = vv;
        }
        #pragma unroll
        for (int i = 0; i < 8; ++i) {
            int e4 = tid + i * 256, row = e4 >> 3, c4 = e4 & 7;
            const float4 bv = *(const float4*)(Bbase + (size_t)row * SEQ + k0 + c4 * 4);
            const int4   mv = *(const int4*)  (Mbase + (size_t)row * SEQ + k0 + c4 * 4);
            float* dst = &Bsf[row][c4 * 4];
            dst[0] = mv.x ? -1e9f : bv.x * LOG2E;
            dst[1] = mv.y ? -1e9f : bv.y * LOG2E;
            dst[2] = mv.z ? -1e9f : bv.z * LOG2E;
            dst[3] = mv.w ? -1e9f : bv.w * LOG2E;
        }
        __syncthreads();
        #pragma unroll 4
        for (int kk = 0; kk < FTK; ++kk) {
            float s = Bsf[tid][kk];
            const float4 k0v = *(const float4*)&Ks[kk][0];
            const float4 k1v = *(const float4*)&Ks[kk][4];
            const float4 k2v = *(const float4*)&Ks[kk][8];
            const float4 k3v = *(const float4*)&Ks[kk][12];
            s = fmaf(Qr[0],  k0v.x, s); s = fmaf(Qr[1],  k0v.y, s);
            s = fmaf(Qr[2],  k0v.z, s); s = fmaf(Qr[3],  k0v.w, s);
            s = fmaf(Qr[4],  k1v.x, s); s = fmaf(Qr[5],  k1v.y, s);
            s = fmaf(Qr[6],  k1v.z, s); s = fmaf(Qr[7],  k1v.w, s);
            s = fmaf(Qr[8],  k2v.x, s); s = fmaf(Qr[9],  k2v.y, s);
            s = fmaf(Qr[10], k2v.z, s); s = fmaf(Qr[11], k2v.w, s);
            s = fmaf(Qr[12], k3v.x, s); s = fmaf(Qr[13], k3v.y, s);
            s = fmaf(Qr[14], k3v.z, s); s = fmaf(Qr[15], k3v.w, s);
            float p = fast_exp2(s);
            l += p;
            const float4 v0 = *(const float4*)&Vs[kk][0];
            const float4 v1 = *(const float4*)&Vs[kk][4];
            const float4 v2 = *(const float4*)&Vs[kk][8];
            const float4 v3 = *(const float4*)&Vs[kk][12];
            acc[0]  = fmaf(p, v0.x, acc[0]);  acc[1]  = fmaf(p, v0.y, acc[1]);
            acc[2]  = fmaf(p, v0.z, acc[2]);  acc[3]  = fmaf(p, v0.w, acc[3]);
            acc[4]  = fmaf(p, v1.x, acc[4]);  acc[5]  = fmaf(p, v1.y, acc[5]);
            acc[6]  = fmaf(p, v1.z, acc[6]);  acc[7]  = fmaf(p, v1.w, acc[7]);
            acc[8]  = fmaf(p, v2.x, acc[8]);  acc[9]  = fmaf(p, v2.y, acc[9]);
            acc[10] = fmaf(p, v2.z, acc[10]); acc[11] = fmaf(p, v2.w, acc[11]);
            acc[12] = fmaf(p, v3.x, acc[12]); acc[13] = fmaf(p, v3.y, acc[13]);
            acc[14] = fmaf(p, v3.z, acc[14]); acc[15] = fmaf(p, v3.w, acc[15]);
        }
        __syncthreads();
    }
    const float inv = 1.0f / l;
    float4* o4 = (float4*)(out + (bh * SEQ + q0 + tid) * DK);
    #pragma unroll
    for (int i = 0; i < 4; ++i) {
        float4 v;
        v.x = acc[4*i+0] * inv; v.y = acc[4*i+1] * inv;
        v.z = acc[4*i+2] * inv; v.w = acc[4*i+3] * inv;
        o4[i] = v;
    }
}

extern "C" void kernel_launch(void* const* d_in, const int* in_sizes, int n_in,
                              void* d_out, int out_size, void* d_ws, size_t ws_size,
                              hipStream_t stream) {
    const float* Q    = (const float*)d_in[0];
    const float* K    = (const float*)d_in[1];
    const float* V    = (const float*)d_in[2];
    const int*   mask = (const int*)  d_in[3];
    const float* bias = (const float*)d_in[4];
    float* out = (float*)d_out;

    const size_t nElem   = (size_t)NBATCH * NHEAD * SEQ * DK;   // 2,097,152
    const size_t bfBytes = nElem * sizeof(short);               // 4 MB each
    const size_t accBytes = (size_t)KQ * NROWS * DK * sizeof(float);  // 33.55 MB
    const size_t lBytes   = (size_t)KQ * NROWS * sizeof(float);       //  2.10 MB
    const size_t need = 5 * bfBytes + accBytes + lBytes;        // 56.6 MB

    if (ws_size >= need) {
        char* w = (char*)d_ws;
        short* Qhi = (short*)(w);
        short* Qlo = (short*)(w + 1 * bfBytes);
        short* Khi = (short*)(w + 2 * bfBytes);
        short* Klo = (short*)(w + 3 * bfBytes);
        short* Vt  = (short*)(w + 4 * bfBytes);
        float* accW = (float*)(w + 5 * bfBytes);
        float* lW   = (float*)(w + 5 * bfBytes + accBytes);

        prep_qk<<<(int)(nElem / 4 / 256), 256, 0, stream>>>(Q, K, Qhi, Qlo, Khi, Klo);
        prep_vt<<<NBATCH * NHEAD * (SEQ / 64), 256, 0, stream>>>(V, Vt);
        sdpa_mfma_pass1<<<NBATCH * 16 * KQ, 256, 0, stream>>>(Qhi, Qlo, Khi, Klo, Vt,
                                                              mask, bias, accW, lW);
        sdpa_pass2<<<(NROWS * DK / 4) / 256, 256, 0, stream>>>(accW, lW, out);
    } else {
        sdpa_fallback<<<NBATCH * NHEAD * (SEQ / FTQ), FTQ, 0, stream>>>(Q, K, V, mask, bias, out);
    }
}